// Round 2
// baseline (2516.286 us; speedup 1.0000x reference)
//
#include <hip/hip_runtime.h>
#include <hip/hip_bf16.h>

typedef __attribute__((ext_vector_type(8))) __bf16 bf16x8;
typedef __attribute__((ext_vector_type(4))) float  f32x4;

#define SCOPE_AGENT __HIP_MEMORY_SCOPE_AGENT

static __device__ __forceinline__ f32x4 mfma16(bf16x8 a, bf16x8 b, f32x4 c) {
    return __builtin_amdgcn_mfma_f32_16x16x32_bf16(a, b, c, 0, 0, 0);
}
static __device__ __forceinline__ float sigm(float x)  { return 1.0f / (1.0f + __expf(-x)); }
static __device__ __forceinline__ float tanh_(float x) { return 1.0f - 2.0f / (__expf(2.0f * x) + 1.0f); }

// load 8 consecutive f32, convert to bf16x8 (two dwordx4 + packed cvt)
static __device__ __forceinline__ bf16x8 cvt8(const float* __restrict__ p) {
    const float4* q = (const float4*)p;
    float4 a = q[0], b = q[1];
    bf16x8 r;
    r[0] = (__bf16)a.x; r[1] = (__bf16)a.y; r[2] = (__bf16)a.z; r[3] = (__bf16)a.w;
    r[4] = (__bf16)b.x; r[5] = (__bf16)b.y; r[6] = (__bf16)b.z; r[7] = (__bf16)b.w;
    return r;
}

static __device__ __forceinline__ void st_agent_u32(unsigned int* p, unsigned int v) {
    __hip_atomic_store(p, v, __ATOMIC_RELAXED, SCOPE_AGENT);
}
static __device__ __forceinline__ unsigned int ld_agent_u32(const unsigned int* p) {
    return __hip_atomic_load((unsigned int*)p, __ATOMIC_RELAXED, SCOPE_AGENT);
}

// ---------------------------------------------------------------------------
// LSTM: 5 layers x 2 directions. 4 active workgroups (2 per direction), each
// owns 128 cells (512 gate rows). Whh fragments (converted f32->bf16) live in
// registers across all 64 steps. Per-step h-half exchange via agent atomics.
// ---------------------------------------------------------------------------
__global__ __launch_bounds__(1024, 4) void lstm_kernel(
    const float* __restrict__ audio,   // [64][768] f32
    const float* __restrict__ Wih0,    // [2][1024][768] f32
    const float* __restrict__ Whh0,    // [2][1024][256] f32
    const float* __restrict__ b0,      // [2][1024] f32
    const float* __restrict__ WihL,    // [4][2][1024][512] f32
    const float* __restrict__ WhhL,    // [4][2][1024][256] f32
    const float* __restrict__ bL,      // [4][2][1024] f32
    float*        __restrict__ Gx_all, // ws [4][64][512] f32
    unsigned int* __restrict__ exch,   // ws [4][64][64] u32
    unsigned int* __restrict__ flags,  // ws: flags[0..3], gbar at [16]
    unsigned short* __restrict__ zbuf) // ws [5][64][512] bf16 bits
{
    const int bid = blockIdx.x;
    const int sub = bid & 7;
    if (sub >= 2) return;
    const int dir  = sub;
    const int half = bid >> 3;
    const int wg   = dir * 2 + half;
    const int peer = dir * 2 + (1 - half);
    const int tid  = threadIdx.x;
    const int wave = tid >> 6;
    const int lane = tid & 63;
    const int ln   = lane & 15;
    const int quad = lane >> 4;

    float*              Gx      = Gx_all + (size_t)wg * (64 * 512);
    unsigned int*       exch_me = exch + wg * (64 * 64);
    const unsigned int* exch_pe = exch + peer * (64 * 64);
    unsigned int*       flag_me = flags + wg;
    unsigned int*       flag_pe = flags + peer;
    unsigned int*       gbar    = flags + 16;

    __shared__ __align__(16) unsigned short hbuf[2][256];

    for (int l = 0; l < 5; ++l) {
        if (l > 0) {
            // grid barrier over the 4 active WGs (layer boundary)
            __threadfence();
            __syncthreads();
            if (tid == 0) {
                __hip_atomic_fetch_add(gbar, 1u, __ATOMIC_ACQ_REL, SCOPE_AGENT);
                while (__hip_atomic_load(gbar, __ATOMIC_ACQUIRE, SCOPE_AGENT) < 4u * (unsigned)l)
                    __builtin_amdgcn_s_sleep(1);
            }
            __syncthreads();
        }
        const int Din = l ? 512 : 768;
        const float* Wih_l = l ? (WihL + (size_t)((l - 1) * 2 + dir) * (1024 * 512))
                               : (Wih0 + (size_t)dir * (1024 * 768));
        const float* Whh_l = l ? (WhhL + (size_t)((l - 1) * 2 + dir) * (1024 * 256))
                               : (Whh0 + (size_t)dir * (1024 * 256));
        const float* b_l   = l ? (bL + (size_t)((l - 1) * 2 + dir) * 1024)
                               : (b0 + (size_t)dir * 1024);
        const __bf16* zprev = (const __bf16*)(zbuf + (size_t)(l - 1) * 64 * 512);

        // ---- Phase A: Gx[t][m] = (Wih @ x_t + b) for own 512 rows ----
        // row ordering: m = cell*4 + gate; global weight row r = gate*256 + half*128 + cell
        {
            f32x4 accA[2][4];
            #pragma unroll
            for (int i = 0; i < 2; i++)
                #pragma unroll
                for (int nt = 0; nt < 4; nt++)
                    accA[i][nt] = (f32x4){0.f, 0.f, 0.f, 0.f};
            const int nkc = Din >> 5;
            for (int kc = 0; kc < nkc; ++kc) {
                const int k0 = kc * 32 + quad * 8;
                bf16x8 afr[2];
                #pragma unroll
                for (int i = 0; i < 2; i++) {
                    int m = (wave * 2 + i) * 16 + ln;
                    int r = (m & 3) * 256 + half * 128 + (m >> 2);
                    afr[i] = cvt8(Wih_l + (size_t)r * Din + k0);
                }
                #pragma unroll
                for (int nt = 0; nt < 4; nt++) {
                    const int t = nt * 16 + ln;
                    bf16x8 bfr = l ? *(const bf16x8*)(zprev + (size_t)t * 512 + k0)
                                   : cvt8(audio + (size_t)t * 768 + k0);
                    accA[0][nt] = mfma16(afr[0], bfr, accA[0][nt]);
                    accA[1][nt] = mfma16(afr[1], bfr, accA[1][nt]);
                }
            }
            #pragma unroll
            for (int i = 0; i < 2; i++) {
                const int mt = wave * 2 + i;
                float bv[4];
                #pragma unroll
                for (int reg = 0; reg < 4; reg++)
                    bv[reg] = b_l[reg * 256 + half * 128 + mt * 4 + quad];
                #pragma unroll
                for (int nt = 0; nt < 4; nt++) {
                    const int t = nt * 16 + ln;
                    f32x4 v;
                    #pragma unroll
                    for (int reg = 0; reg < 4; reg++) v[reg] = accA[i][nt][reg] + bv[reg];
                    *(f32x4*)(Gx + (size_t)t * 512 + mt * 16 + quad * 4) = v;
                }
            }
        }
        __syncthreads();

        // ---- load Whh fragments (resident for all 64 steps) ----
        bf16x8 wf[2][8];
        #pragma unroll
        for (int i = 0; i < 2; i++) {
            int m = (wave * 2 + i) * 16 + ln;
            int r = (m & 3) * 256 + half * 128 + (m >> 2);
            #pragma unroll
            for (int j = 0; j < 8; j++) {
                int kc = (j < 4) ? (half * 4 + j) : ((1 - half) * 4 + (j - 4));
                wf[i][j] = cvt8(Whh_l + (size_t)r * 256 + kc * 32 + quad * 8);
            }
        }
        if (tid < 256) { hbuf[0][tid] = 0; hbuf[1][tid] = 0; }
        float cst0 = 0.f, cst1 = 0.f;
        __syncthreads();

        const unsigned fbase = (unsigned)l * 64u;
        unsigned short* zl = zbuf + (size_t)l * 64 * 512;

        for (int s = 0; s < 64; ++s) {
            const int t   = dir ? (63 - s) : s;
            const int cur = s & 1, nxt = cur ^ 1;
            f32x4 acc0 = (f32x4){0.f, 0.f, 0.f, 0.f};
            f32x4 acc1 = (f32x4){0.f, 0.f, 0.f, 0.f};

            // own k-half MFMAs (overlaps peer-flag latency)
            #pragma unroll
            for (int j = 0; j < 4; j++) {
                int kc = half * 4 + j;
                bf16x8 bfr = *(const bf16x8*)&hbuf[cur][kc * 32 + quad * 8];
                acc0 = mfma16(wf[0][j], bfr, acc0);
                acc1 = mfma16(wf[1][j], bfr, acc1);
            }
            if (s > 0) {
                if (tid == 0) {
                    while (__hip_atomic_load(flag_pe, __ATOMIC_ACQUIRE, SCOPE_AGENT) < fbase + (unsigned)s)
                        __builtin_amdgcn_s_sleep(1);
                }
                __syncthreads();
                if (tid < 64) {
                    unsigned int u = ld_agent_u32(exch_pe + (s - 1) * 64 + tid);
                    *(unsigned int*)&hbuf[cur][(1 - half) * 128 + 2 * tid] = u;
                }
                __syncthreads();
            }
            // peer k-half MFMAs
            #pragma unroll
            for (int j = 0; j < 4; j++) {
                int kc = (1 - half) * 4 + j;
                bf16x8 bfr = *(const bf16x8*)&hbuf[cur][kc * 32 + quad * 8];
                acc0 = mfma16(wf[0][4 + j], bfr, acc0);
                acc1 = mfma16(wf[1][4 + j], bfr, acc1);
            }
            // cell update: lanes with col==0 own two full cells (gates in 4 acc regs)
            if (ln == 0) {
                #pragma unroll
                for (int i = 0; i < 2; i++) {
                    const int cell = wave * 8 + i * 4 + quad;
                    f32x4 gx = *(const f32x4*)(Gx + (size_t)t * 512 + cell * 4);
                    f32x4 a  = i ? acc1 : acc0;
                    float gi = a[0] + gx[0];
                    float gf = a[1] + gx[1];
                    float gg = a[2] + gx[2];
                    float go = a[3] + gx[3];
                    float cs = (i ? cst1 : cst0);
                    cs = sigm(gf) * cs + sigm(gi) * tanh_(gg);
                    if (i) cst1 = cs; else cst0 = cs;
                    float h = sigm(go) * tanh_(cs);
                    __bf16 hv = (__bf16)h;
                    unsigned short hb = __builtin_bit_cast(unsigned short, hv);
                    hbuf[nxt][half * 128 + cell] = hb;
                    zl[(size_t)t * 512 + dir * 256 + half * 128 + cell] = hb;
                }
            }
            __syncthreads();
            if (tid < 64) {
                unsigned int u = *(const unsigned int*)&hbuf[nxt][half * 128 + 2 * tid];
                st_agent_u32(exch_me + s * 64 + tid, u);
            }
            __syncthreads();
            if (tid == 0)
                __hip_atomic_fetch_add(flag_me, 1u, __ATOMIC_RELEASE, SCOPE_AGENT);
        }
    }
}

// ---------------------------------------------------------------------------
// fc: [64,512]bf16 @ W[2560,512]f32 -> x4b as [20][64][128] bf16. Grid = 40.
// ---------------------------------------------------------------------------
__global__ __launch_bounds__(256) void fc_kernel(
    const __bf16* __restrict__ zb, const float* __restrict__ W,
    const float* __restrict__ bb, __bf16* __restrict__ out)
{
    const int tid = threadIdx.x;
    const int wave = tid >> 6, lane = tid & 63, ln = lane & 15, quad = lane >> 4;
    const int nbase = blockIdx.x * 64;
    f32x4 acc[4];
    #pragma unroll
    for (int nt = 0; nt < 4; nt++) acc[nt] = (f32x4){0.f, 0.f, 0.f, 0.f};
    #pragma unroll 2
    for (int kc = 0; kc < 16; kc++) {
        const int k0 = kc * 32 + quad * 8;
        bf16x8 a = *(const bf16x8*)(zb + (size_t)(wave * 16 + ln) * 512 + k0);
        #pragma unroll
        for (int nt = 0; nt < 4; nt++) {
            bf16x8 b = cvt8(W + (size_t)(nbase + nt * 16 + ln) * 512 + k0);
            acc[nt] = mfma16(a, b, acc[nt]);
        }
    }
    #pragma unroll
    for (int nt = 0; nt < 4; nt++) {
        const int n = nbase + nt * 16 + ln;
        const float bv = bb[n];
        #pragma unroll
        for (int reg = 0; reg < 4; reg++) {
            const int t = wave * 16 + quad * 4 + reg;
            out[(size_t)((n >> 7) * 64 + t) * 128 + (n & 127)] = (__bf16)(acc[nt][reg] + bv);
        }
    }
}

// ---------------------------------------------------------------------------
// pool: out[r][t][:] = sum_{s=0..2} vals[3r+s] * in[cols[3r+s]][t][:]
// ---------------------------------------------------------------------------
template <int C>
__global__ __launch_bounds__(256) void pool_kernel(
    const __bf16* __restrict__ in, __bf16* __restrict__ out,
    const int* __restrict__ cols, const float* __restrict__ vals, int V)
{
    const int P = 64 * C / 8;
    const int gid = blockIdx.x * 256 + threadIdx.x;
    if (gid >= V * P) return;
    const int r = gid / P;
    const int rem = gid - r * P;   // rem*8 == t*C + c8*8
    float acc[8] = {0.f, 0.f, 0.f, 0.f, 0.f, 0.f, 0.f, 0.f};
    #pragma unroll
    for (int s = 0; s < 3; s++) {
        const int col = cols[3 * r + s];
        const float vv = vals[3 * r + s];
        bf16x8 x = *(const bf16x8*)(in + (size_t)col * 64 * C + rem * 8);
        #pragma unroll
        for (int e = 0; e < 8; e++) acc[e] += vv * (float)x[e];
    }
    bf16x8 ov;
    #pragma unroll
    for (int e = 0; e < 8; e++) ov[e] = (__bf16)acc[e];
    *(bf16x8*)(out + (size_t)r * 64 * C + rem * 8) = ov;
}

// ---------------------------------------------------------------------------
// spiral conv + ELU: one vertex per block, 4 waves = 4 t-tiles of 16.
// in: [Vin][64][CIN] bf16, W: [COUT][9*CIN] f32, out: [V][64][COUT] bf16
// ---------------------------------------------------------------------------
template <int CIN, int COUT>
__global__ __launch_bounds__(256) void conv_kernel(
    const __bf16* __restrict__ in, __bf16* __restrict__ out,
    const int* __restrict__ idx, const float* __restrict__ W,
    const float* __restrict__ bias)
{
    constexpr int K = 9 * CIN;
    constexpr int NT = COUT / 16;
    constexpr int NKC = K / 32;
    const int v = blockIdx.x;
    const int tid = threadIdx.x;
    const int wave = tid >> 6, lane = tid & 63, ln = lane & 15, quad = lane >> 4;
    __shared__ int sIdx[9];
    if (tid < 9) sIdx[tid] = idx[v * 9 + tid];
    __syncthreads();
    f32x4 acc[NT];
    #pragma unroll
    for (int nt = 0; nt < NT; nt++) acc[nt] = (f32x4){0.f, 0.f, 0.f, 0.f};
    const int tt = wave * 16 + ln;
    for (int kc = 0; kc < NKC; kc++) {
        const int k0 = kc * 32;
        const int l = k0 / CIN;                 // power-of-two CIN -> shift
        const int c = (k0 & (CIN - 1)) + quad * 8;
        const int row = sIdx[l];
        bf16x8 a = *(const bf16x8*)(in + ((size_t)row * 64 + tt) * CIN + c);
        #pragma unroll
        for (int nt = 0; nt < NT; nt++) {
            bf16x8 b = cvt8(W + (size_t)(nt * 16 + ln) * K + k0 + quad * 8);
            acc[nt] = mfma16(a, b, acc[nt]);
        }
    }
    #pragma unroll
    for (int nt = 0; nt < NT; nt++) {
        const int n = nt * 16 + ln;
        const float bv = bias[n];
        #pragma unroll
        for (int reg = 0; reg < 4; reg++) {
            const int t = wave * 16 + quad * 4 + reg;
            float val = acc[nt][reg] + bv;
            val = val > 0.f ? val : (__expf(val) - 1.f);   // ELU
            out[((size_t)v * 64 + t) * COUT + n] = (__bf16)val;
        }
    }
}

// ---------------------------------------------------------------------------
// head: spiral conv to 3 channels + actor offset, writes [64][5023][3] f32
// ---------------------------------------------------------------------------
__global__ __launch_bounds__(256) void head_kernel(
    const __bf16* __restrict__ in, float* __restrict__ out,
    const int* __restrict__ idx, const float* __restrict__ W,
    const float* __restrict__ bias, const float* __restrict__ actor)
{
    const int v = blockIdx.x;
    const int tid = threadIdx.x;
    const int wave = tid >> 6, lane = tid & 63, ln = lane & 15, quad = lane >> 4;
    __shared__ int sIdx[9];
    if (tid < 9) sIdx[tid] = idx[v * 9 + tid];
    __syncthreads();
    f32x4 acc = (f32x4){0.f, 0.f, 0.f, 0.f};
    const int tt = wave * 16 + ln;
    const int rown = ln < 3 ? ln : 0;
    #pragma unroll
    for (int kc = 0; kc < 9; kc++) {
        const int row = sIdx[kc];
        bf16x8 a = *(const bf16x8*)(in + ((size_t)row * 64 + tt) * 32 + quad * 8);
        bf16x8 b = cvt8(W + (size_t)rown * 288 + kc * 32 + quad * 8);
        acc = mfma16(a, b, acc);
    }
    if (ln < 3) {
        const float bv = bias[ln];
        const float av = actor[v * 3 + ln];
        #pragma unroll
        for (int reg = 0; reg < 4; reg++) {
            const int t = wave * 16 + quad * 4 + reg;
            out[((size_t)t * 5023 + v) * 3 + ln] = acc[reg] + bv + av;
        }
    }
}

// ---------------------------------------------------------------------------
// ws layout (bytes):
//   0        : flags[4] + gbar (memset to 0 each launch; first 1024 B)
//   1024     : exch   [4][64][64] u32           (65536)
//   66560    : Gx     [4][64][512] f32          (524288)
//   590848   : zbuf   [5][64][512] bf16         (327680)
//   918528   : arenaA (max 20574208 = conv0 out)
//   21492736 : arenaB (max 41148416 = pool0 out)   total ~59.8 MB
// ---------------------------------------------------------------------------
extern "C" void kernel_launch(void* const* d_in, const int* in_sizes, int n_in,
                              void* d_out, int out_size, void* d_ws, size_t ws_size,
                              hipStream_t stream) {
    const float* audio = (const float*)d_in[0];
    const float* actor = (const float*)d_in[1];
    const float* Wih0  = (const float*)d_in[2];
    const float* Whh0  = (const float*)d_in[3];
    const float* b0    = (const float*)d_in[4];
    const float* WihL  = (const float*)d_in[5];
    const float* WhhL  = (const float*)d_in[6];
    const float* bLs   = (const float*)d_in[7];
    const float* fcW   = (const float*)d_in[8];
    const float* fcb   = (const float*)d_in[9];
    const float* c3W = (const float*)d_in[10]; const float* c3b = (const float*)d_in[11];
    const float* c2W = (const float*)d_in[12]; const float* c2b = (const float*)d_in[13];
    const float* c1W = (const float*)d_in[14]; const float* c1b = (const float*)d_in[15];
    const float* c0W = (const float*)d_in[16]; const float* c0b = (const float*)d_in[17];
    const float* hW  = (const float*)d_in[18]; const float* hb  = (const float*)d_in[19];
    const int* idx0 = (const int*)d_in[20];
    const int* idx1 = (const int*)d_in[21];
    const int* idx2 = (const int*)d_in[22];
    const int* idx3 = (const int*)d_in[23];
    const int* cols0 = (const int*)d_in[25]; const float* vals0 = (const float*)d_in[26];
    const int* cols1 = (const int*)d_in[28]; const float* vals1 = (const float*)d_in[29];
    const int* cols2 = (const int*)d_in[31]; const float* vals2 = (const float*)d_in[32];
    const int* cols3 = (const int*)d_in[34]; const float* vals3 = (const float*)d_in[35];

    char* ws = (char*)d_ws;
    unsigned int*   flags = (unsigned int*)ws;
    unsigned int*   exch  = (unsigned int*)(ws + 1024);
    float*          Gx    = (float*)(ws + 66560);
    unsigned short* zbuf  = (unsigned short*)(ws + 590848);
    char* arenaA = ws + 918528;
    char* arenaB = ws + 21492736;

    __bf16* x4b = (__bf16*)arenaA;   // [20][64][128]
    __bf16* p3  = (__bf16*)arenaB;   // [79][64][128]
    __bf16* c3o = (__bf16*)arenaA;   // [79][64][128]
    __bf16* p2  = (__bf16*)arenaB;   // [314][64][128]
    __bf16* c2o = (__bf16*)arenaA;   // [314][64][64]
    __bf16* p1  = (__bf16*)arenaB;   // [1256][64][64]
    __bf16* c1o = (__bf16*)arenaA;   // [1256][64][64]
    __bf16* p0  = (__bf16*)arenaB;   // [5023][64][64]
    __bf16* c0o = (__bf16*)arenaA;   // [5023][64][32]

    hipMemsetAsync(d_ws, 0, 1024, stream);   // flags + grid barrier

    lstm_kernel<<<16, 1024, 0, stream>>>(audio, Wih0, Whh0, b0, WihL, WhhL, bLs,
                                         Gx, exch, flags, zbuf);
    fc_kernel<<<40, 256, 0, stream>>>((const __bf16*)(zbuf + (size_t)4 * 64 * 512), fcW, fcb, x4b);

    { int n = 79 * 64 * 128 / 8;
      pool_kernel<128><<<(n + 255) / 256, 256, 0, stream>>>(x4b, p3, cols3, vals3, 79);
      conv_kernel<128, 128><<<79, 256, 0, stream>>>(p3, c3o, idx3, c3W, c3b); }
    { int n = 314 * 64 * 128 / 8;
      pool_kernel<128><<<(n + 255) / 256, 256, 0, stream>>>(c3o, p2, cols2, vals2, 314);
      conv_kernel<128, 64><<<314, 256, 0, stream>>>(p2, c2o, idx2, c2W, c2b); }
    { int n = 1256 * 64 * 64 / 8;
      pool_kernel<64><<<(n + 255) / 256, 256, 0, stream>>>(c2o, p1, cols1, vals1, 1256);
      conv_kernel<64, 64><<<1256, 256, 0, stream>>>(p1, c1o, idx1, c1W, c1b); }
    { int n = 5023 * 64 * 64 / 8;
      pool_kernel<64><<<(n + 255) / 256, 256, 0, stream>>>(c1o, p0, cols0, vals0, 5023);
      conv_kernel<64, 32><<<5023, 256, 0, stream>>>(p0, c0o, idx0, c0W, c0b); }

    head_kernel<<<5023, 256, 0, stream>>>(c0o, (float*)d_out, idx0, hW, hb, actor);
}

// Round 3
// 2032.014 us; speedup vs baseline: 1.2383x; 1.2383x over previous
//
#include <hip/hip_runtime.h>
#include <hip/hip_bf16.h>

typedef __attribute__((ext_vector_type(8))) __bf16 bf16x8;
typedef __attribute__((ext_vector_type(4))) float  f32x4;

#define SCOPE_AGENT __HIP_MEMORY_SCOPE_AGENT
#define POISON 0xAAAAAAAAu

static __device__ __forceinline__ f32x4 mfma16(bf16x8 a, bf16x8 b, f32x4 c) {
    return __builtin_amdgcn_mfma_f32_16x16x32_bf16(a, b, c, 0, 0, 0);
}
static __device__ __forceinline__ float sigm(float x)  { return 1.0f / (1.0f + __expf(-x)); }
static __device__ __forceinline__ float tanh_(float x) { return 1.0f - 2.0f / (__expf(2.0f * x) + 1.0f); }

static __device__ __forceinline__ bf16x8 cvt8(const float* __restrict__ p) {
    const float4* q = (const float4*)p;
    float4 a = q[0], b = q[1];
    bf16x8 r;
    r[0] = (__bf16)a.x; r[1] = (__bf16)a.y; r[2] = (__bf16)a.z; r[3] = (__bf16)a.w;
    r[4] = (__bf16)b.x; r[5] = (__bf16)b.y; r[6] = (__bf16)b.z; r[7] = (__bf16)b.w;
    return r;
}

static __device__ __forceinline__ void st_agent_u32(unsigned int* p, unsigned int v) {
    __hip_atomic_store(p, v, __ATOMIC_RELAXED, SCOPE_AGENT);
}
static __device__ __forceinline__ unsigned long long ld_agent_u64(const unsigned long long* p) {
    return __hip_atomic_load((unsigned long long*)p, __ATOMIC_RELAXED, SCOPE_AGENT);
}
static __device__ __forceinline__ bool chk64(unsigned long long v) {
    return ((unsigned)v != POISON) & ((unsigned)(v >> 32) != POISON);
}
union b64u { unsigned long long q[2]; bf16x8 v; };
union g4u  { unsigned long long q; __bf16 h[4]; };

// ws layout (bytes):
//   0       done[20] u32 (write-once, poison-init; pad to 256)
//   256     exch [4 wg][5 l][64 s][64 u32]      = 327,680   (payload-is-flag slots)
//   327936  Gx   [4 wg][64 t][512 m] bf16       = 262,144
//   590080  zbuf [2][64][512] bf16 (ping-pong)  = 131,072
//   721152  arenaA (20,574,208)   [fcWb overlay at +393,216, dead after fc]
//   21295360 arenaB (41,148,416)  [lstm bf16 weights overlay, dead after lstm]
//   convWb overlays exch+Gx region (ws+256), written AFTER lstm.  total 62.44 MB
#define DONE_OFF   0
#define EXCH_OFF   256
#define GX_OFF     327936
#define ZBUF_OFF   590080
#define ARENA_A    721152
#define ARENA_B    21295360

// lstm bf16 weight offsets within arenaB (elements)
#define OW0 0
#define OWL 1572864
#define OH0 5767168
#define OHL 6291456

// ---------------------------------------------------------------------------
// one-time f32 -> bf16 weight conversion (LSTM weights -> arenaB)
// ---------------------------------------------------------------------------
__global__ __launch_bounds__(256) void precvt_lstm(
    const float* __restrict__ Wih0, const float* __restrict__ WihL,
    const float* __restrict__ Whh0, const float* __restrict__ WhhL,
    __bf16* __restrict__ out)
{
    int f = (blockIdx.x * 256 + threadIdx.x) * 4;
    const float* src; int off;
    if (f < 1572864)      { src = Wih0; off = f; }
    else if (f < 5767168) { src = WihL; off = f - 1572864; }
    else if (f < 6291456) { src = Whh0; off = f - 5767168; }
    else                  { src = WhhL; off = f - 6291456; }
    float4 v = *(const float4*)(src + off);
    g4u u;
    u.h[0] = (__bf16)v.x; u.h[1] = (__bf16)v.y; u.h[2] = (__bf16)v.z; u.h[3] = (__bf16)v.w;
    *(unsigned long long*)(out + f) = u.q;
}

// decoder weights: fcW -> fcWb, conv/head weights -> convWb (concat order c3,c2,c1,c0,hW)
__global__ __launch_bounds__(256) void precvt_dec(
    const float* __restrict__ fcW, const float* __restrict__ c3W,
    const float* __restrict__ c2W, const float* __restrict__ c1W,
    const float* __restrict__ c0W, const float* __restrict__ hW,
    __bf16* __restrict__ fcWb, __bf16* __restrict__ convWb)
{
    int f = (blockIdx.x * 256 + threadIdx.x) * 4;
    if (f >= 1588064) return;
    const float* src; int off; __bf16* dst; int doff;
    if (f < 1310720) { src = fcW; off = f; dst = fcWb; doff = f; }
    else {
        int g = f - 1310720; dst = convWb; doff = g;
        if (g < 147456)      { src = c3W; off = g; }
        else if (g < 221184) { src = c2W; off = g - 147456; }
        else if (g < 258048) { src = c1W; off = g - 221184; }
        else if (g < 276480) { src = c0W; off = g - 258048; }
        else                 { src = hW;  off = g - 276480; }
    }
    float4 v = *(const float4*)(src + off);
    g4u u;
    u.h[0] = (__bf16)v.x; u.h[1] = (__bf16)v.y; u.h[2] = (__bf16)v.z; u.h[3] = (__bf16)v.w;
    *(unsigned long long*)(dst + doff) = u.q;
}

// ---------------------------------------------------------------------------
// LSTM: 5 layers x 2 dirs, 2 WGs per direction (bid&7 = dir, bid>>3 = half so
// pairs {p,p+8} share an XCD under round-robin). Whh bf16 fragments resident
// in registers. Per-step h-half exchange: payload-is-the-flag — producer
// lanes atomic-store h-pairs at update time; consumer spins on relaxed
// agent loads until all dwords != poison. One __syncthreads per step.
// k-dim of Whh is permuted so each ln==0 lane's two cells are adjacent:
// perm position 2*(w*4+q)+i  <->  natural cell w*8+i*4+q   (per half).
// ---------------------------------------------------------------------------
__global__ __launch_bounds__(1024, 4) void lstm_kernel(
    const float* __restrict__ audio,
    const __bf16* __restrict__ Wih0b, const __bf16* __restrict__ WihLb,
    const __bf16* __restrict__ Whh0b, const __bf16* __restrict__ WhhLb,
    const float* __restrict__ b0, const float* __restrict__ bL,
    __bf16* __restrict__ Gx_all,        // [4][64][512] bf16
    unsigned int* __restrict__ exch,    // [4][5][64][64] u32
    unsigned int* __restrict__ done,    // [20] u32
    unsigned short* __restrict__ zbuf)  // [2][64][512] bf16 bits
{
    const int bid = blockIdx.x;
    const int sub = bid & 7;
    if (sub >= 2) return;
    const int dir  = sub;
    const int half = bid >> 3;
    const int wg   = dir * 2 + half;
    const int peer = dir * 2 + (1 - half);
    const int tid  = threadIdx.x;
    const int wave = tid >> 6;
    const int lane = tid & 63;
    const int ln   = lane & 15;
    const int quad = lane >> 4;

    __bf16* Gx = Gx_all + (size_t)wg * (64 * 512);
    __shared__ __align__(16) unsigned short hbuf[2][128];

    for (int l = 0; l < 5; ++l) {
        if (l > 0) {
            // layer barrier across the 4 WGs (also publishes zbuf via threadfence)
            if (tid == 0) {
                __threadfence();
                __hip_atomic_store(&done[(l - 1) * 4 + wg], 1u, __ATOMIC_RELEASE, SCOPE_AGENT);
                #pragma unroll
                for (int w = 0; w < 4; w++) {
                    if (w == wg) continue;
                    while (__hip_atomic_load(&done[(l - 1) * 4 + w], __ATOMIC_RELAXED, SCOPE_AGENT) != 1u)
                        __builtin_amdgcn_s_sleep(1);
                }
                (void)__hip_atomic_load(&done[(l - 1) * 4 + peer], __ATOMIC_ACQUIRE, SCOPE_AGENT);
            }
            __syncthreads();
        }
        const int Din = l ? 512 : 768;
        const __bf16* Wih_l = l ? (WihLb + (size_t)((l - 1) * 2 + dir) * (1024 * 512))
                                : (Wih0b + (size_t)dir * (1024 * 768));
        const __bf16* Whh_l = l ? (WhhLb + (size_t)((l - 1) * 2 + dir) * (1024 * 256))
                                : (Whh0b + (size_t)dir * (1024 * 256));
        const float* b_l    = l ? (bL + (size_t)((l - 1) * 2 + dir) * 1024)
                                : (b0 + (size_t)dir * 1024);
        const __bf16* zprev = (const __bf16*)(zbuf + (size_t)((l - 1) & 1) * 64 * 512);

        // ---- Phase A: Gx[t][m] = Wih @ x_t + b (own 512 rows, bf16 out) ----
        // m = cell_local*4 + gate; weight row r = gate*256 + half*128 + cell_local
        {
            f32x4 accA[2][4];
            #pragma unroll
            for (int i = 0; i < 2; i++)
                #pragma unroll
                for (int nt = 0; nt < 4; nt++)
                    accA[i][nt] = (f32x4){0.f, 0.f, 0.f, 0.f};
            const int nkc = Din >> 5;
            for (int kc = 0; kc < nkc; ++kc) {
                const int k0 = kc * 32 + quad * 8;
                bf16x8 afr[2];
                #pragma unroll
                for (int i = 0; i < 2; i++) {
                    int m = (wave * 2 + i) * 16 + ln;
                    int r = (m & 3) * 256 + half * 128 + (m >> 2);
                    afr[i] = *(const bf16x8*)(Wih_l + (size_t)r * Din + k0);
                }
                #pragma unroll
                for (int nt = 0; nt < 4; nt++) {
                    const int t = nt * 16 + ln;
                    bf16x8 bfr = l ? *(const bf16x8*)(zprev + (size_t)t * 512 + k0)
                                   : cvt8(audio + (size_t)t * 768 + k0);
                    accA[0][nt] = mfma16(afr[0], bfr, accA[0][nt]);
                    accA[1][nt] = mfma16(afr[1], bfr, accA[1][nt]);
                }
            }
            #pragma unroll
            for (int i = 0; i < 2; i++) {
                const int mt = wave * 2 + i;
                float bv[4];
                #pragma unroll
                for (int reg = 0; reg < 4; reg++)
                    bv[reg] = b_l[reg * 256 + half * 128 + mt * 4 + quad];
                #pragma unroll
                for (int nt = 0; nt < 4; nt++) {
                    const int t = nt * 16 + ln;
                    g4u u;
                    #pragma unroll
                    for (int reg = 0; reg < 4; reg++) u.h[reg] = (__bf16)(accA[i][nt][reg] + bv[reg]);
                    *(unsigned long long*)(Gx + (size_t)t * 512 + mt * 16 + quad * 4) = u.q;
                }
            }
        }
        __syncthreads();

        // ---- Whh fragments, k-permuted (resident for all 64 steps) ----
        bf16x8 wf[2][8];
        #pragma unroll
        for (int i = 0; i < 2; i++) {
            int m = (wave * 2 + i) * 16 + ln;
            int r = (m & 3) * 256 + half * 128 + (m >> 2);
            const __bf16* wr = Whh_l + (size_t)r * 256;
            #pragma unroll
            for (int j = 0; j < 8; j++) {
                int cg = (j < 4) ? (half * 4 + j) : ((1 - half) * 4 + (j - 4));
                bf16x8 f;
                #pragma unroll
                for (int p = 0; p < 8; p++) {
                    int g = cg * 32 + quad * 8 + p;
                    int x = g & 127;
                    int col = (g >> 7) * 128 + ((x >> 3)) * 8 + (x & 1) * 4 + ((x >> 1) & 3);
                    f[p] = wr[col];
                }
                wf[i][j] = f;
            }
        }
        if (tid < 64) ((unsigned int*)hbuf[0])[tid] = 0;
        float cst0 = 0.f, cst1 = 0.f;
        __syncthreads();

        unsigned int* exch_me_l = exch + (size_t)((wg * 5 + l) * 64) * 64;
        const unsigned long long* exch_pe_l =
            (const unsigned long long*)(exch + (size_t)((peer * 5 + l) * 64) * 64);
        unsigned short* zl = zbuf + (size_t)(l & 1) * 64 * 512;

        for (int s = 0; s < 64; ++s) {
            const int t   = dir ? (63 - s) : s;
            const int cur = s & 1, nxt = cur ^ 1;
            f32x4 acc0 = (f32x4){0.f, 0.f, 0.f, 0.f};
            f32x4 acc1 = (f32x4){0.f, 0.f, 0.f, 0.f};

            // own-half MFMAs from LDS (permuted layout)
            #pragma unroll
            for (int j = 0; j < 4; j++) {
                bf16x8 bfr = *(const bf16x8*)&hbuf[cur][j * 32 + quad * 8];
                acc0 = mfma16(wf[0][j], bfr, acc0);
                acc1 = mfma16(wf[1][j], bfr, acc1);
            }
            if (s > 0) {
                const unsigned long long* slot = exch_pe_l + (size_t)(s - 1) * 32;
                #pragma unroll
                for (int jj = 0; jj < 4; jj += 2) {
                    unsigned long long p0, p1, p2, p3; bool ok;
                    do {
                        p0 = ld_agent_u64(slot + jj * 8 + quad * 2);
                        p1 = ld_agent_u64(slot + jj * 8 + quad * 2 + 1);
                        p2 = ld_agent_u64(slot + (jj + 1) * 8 + quad * 2);
                        p3 = ld_agent_u64(slot + (jj + 1) * 8 + quad * 2 + 1);
                        ok = chk64(p0) & chk64(p1) & chk64(p2) & chk64(p3);
                    } while (!__all(ok));
                    b64u ba, bb;
                    ba.q[0] = p0; ba.q[1] = p1;
                    bb.q[0] = p2; bb.q[1] = p3;
                    acc0 = mfma16(wf[0][4 + jj], ba.v, acc0);
                    acc1 = mfma16(wf[1][4 + jj], ba.v, acc1);
                    acc0 = mfma16(wf[0][5 + jj], bb.v, acc0);
                    acc1 = mfma16(wf[1][5 + jj], bb.v, acc1);
                }
            }
            if (ln == 0) {
                const __bf16* gx = Gx + (size_t)t * 512;
                const int c0 = wave * 8 + quad, c1 = c0 + 4;
                g4u u0, u1;
                u0.q = *(const unsigned long long*)(gx + c0 * 4);
                u1.q = *(const unsigned long long*)(gx + c1 * 4);
                float gi0 = acc0[0] + (float)u0.h[0], gf0 = acc0[1] + (float)u0.h[1];
                float gg0 = acc0[2] + (float)u0.h[2], go0 = acc0[3] + (float)u0.h[3];
                float gi1 = acc1[0] + (float)u1.h[0], gf1 = acc1[1] + (float)u1.h[1];
                float gg1 = acc1[2] + (float)u1.h[2], go1 = acc1[3] + (float)u1.h[3];
                cst0 = sigm(gf0) * cst0 + sigm(gi0) * tanh_(gg0);
                cst1 = sigm(gf1) * cst1 + sigm(gi1) * tanh_(gg1);
                float h0 = sigm(go0) * tanh_(cst0);
                float h1 = sigm(go1) * tanh_(cst1);
                unsigned short hb0 = __builtin_bit_cast(unsigned short, (__bf16)h0);
                unsigned short hb1 = __builtin_bit_cast(unsigned short, (__bf16)h1);
                unsigned int hpair = (unsigned int)hb0 | ((unsigned int)hb1 << 16);
                const int jp = wave * 4 + quad;                 // pair index 0..63
                *(unsigned int*)&hbuf[nxt][2 * jp] = hpair;     // LDS (permuted)
                st_agent_u32(exch_me_l + s * 64 + jp, hpair);   // publish (payload = flag)
                zl[(size_t)t * 512 + dir * 256 + half * 128 + c0] = hb0;
                zl[(size_t)t * 512 + dir * 256 + half * 128 + c1] = hb1;
            }
            __syncthreads();
        }
    }
}

// ---------------------------------------------------------------------------
// fc: zb[64,512]bf16 @ Wb[2560,512]bf16 -> x4b [20][64][128] bf16. Grid = 40.
// ---------------------------------------------------------------------------
__global__ __launch_bounds__(256) void fc_kernel(
    const __bf16* __restrict__ zb, const __bf16* __restrict__ W,
    const float* __restrict__ bb, __bf16* __restrict__ out)
{
    const int tid = threadIdx.x;
    const int wave = tid >> 6, lane = tid & 63, ln = lane & 15, quad = lane >> 4;
    const int nbase = blockIdx.x * 64;
    f32x4 acc[4];
    #pragma unroll
    for (int nt = 0; nt < 4; nt++) acc[nt] = (f32x4){0.f, 0.f, 0.f, 0.f};
    #pragma unroll 2
    for (int kc = 0; kc < 16; kc++) {
        const int k0 = kc * 32 + quad * 8;
        bf16x8 a = *(const bf16x8*)(zb + (size_t)(wave * 16 + ln) * 512 + k0);
        #pragma unroll
        for (int nt = 0; nt < 4; nt++) {
            bf16x8 b = *(const bf16x8*)(W + (size_t)(nbase + nt * 16 + ln) * 512 + k0);
            acc[nt] = mfma16(a, b, acc[nt]);
        }
    }
    #pragma unroll
    for (int nt = 0; nt < 4; nt++) {
        const int n = nbase + nt * 16 + ln;
        const float bv = bb[n];
        #pragma unroll
        for (int reg = 0; reg < 4; reg++) {
            const int t = wave * 16 + quad * 4 + reg;
            out[(size_t)((n >> 7) * 64 + t) * 128 + (n & 127)] = (__bf16)(acc[nt][reg] + bv);
        }
    }
}

// ---------------------------------------------------------------------------
// pool: out[r][t][:] = sum_{s=0..2} vals[3r+s] * in[cols[3r+s]][t][:]
// ---------------------------------------------------------------------------
template <int C>
__global__ __launch_bounds__(256) void pool_kernel(
    const __bf16* __restrict__ in, __bf16* __restrict__ out,
    const int* __restrict__ cols, const float* __restrict__ vals, int V)
{
    const int P = 64 * C / 8;
    const int gid = blockIdx.x * 256 + threadIdx.x;
    if (gid >= V * P) return;
    const int r = gid / P;
    const int rem = gid - r * P;
    float acc[8] = {0.f, 0.f, 0.f, 0.f, 0.f, 0.f, 0.f, 0.f};
    #pragma unroll
    for (int s = 0; s < 3; s++) {
        const int col = cols[3 * r + s];
        const float vv = vals[3 * r + s];
        bf16x8 x = *(const bf16x8*)(in + (size_t)col * 64 * C + rem * 8);
        #pragma unroll
        for (int e = 0; e < 8; e++) acc[e] += vv * (float)x[e];
    }
    bf16x8 ov;
    #pragma unroll
    for (int e = 0; e < 8; e++) ov[e] = (__bf16)acc[e];
    *(bf16x8*)(out + (size_t)r * 64 * C + rem * 8) = ov;
}

// ---------------------------------------------------------------------------
// spiral conv + ELU: one vertex per block. in [Vin][64][CIN] bf16,
// W [COUT][9*CIN] bf16, out [V][64][COUT] bf16.
// ---------------------------------------------------------------------------
template <int CIN, int COUT>
__global__ __launch_bounds__(256) void conv_kernel(
    const __bf16* __restrict__ in, __bf16* __restrict__ out,
    const int* __restrict__ idx, const __bf16* __restrict__ W,
    const float* __restrict__ bias)
{
    constexpr int K = 9 * CIN;
    constexpr int NT = COUT / 16;
    constexpr int NKC = K / 32;
    const int v = blockIdx.x;
    const int tid = threadIdx.x;
    const int wave = tid >> 6, lane = tid & 63, ln = lane & 15, quad = lane >> 4;
    __shared__ int sIdx[9];
    if (tid < 9) sIdx[tid] = idx[v * 9 + tid];
    __syncthreads();
    f32x4 acc[NT];
    #pragma unroll
    for (int nt = 0; nt < NT; nt++) acc[nt] = (f32x4){0.f, 0.f, 0.f, 0.f};
    const int tt = wave * 16 + ln;
    for (int kc = 0; kc < NKC; kc++) {
        const int k0 = kc * 32;
        const int l = k0 / CIN;
        const int c = (k0 & (CIN - 1)) + quad * 8;
        const int row = sIdx[l];
        bf16x8 a = *(const bf16x8*)(in + ((size_t)row * 64 + tt) * CIN + c);
        #pragma unroll
        for (int nt = 0; nt < NT; nt++) {
            bf16x8 b = *(const bf16x8*)(W + (size_t)(nt * 16 + ln) * K + k0 + quad * 8);
            acc[nt] = mfma16(a, b, acc[nt]);
        }
    }
    #pragma unroll
    for (int nt = 0; nt < NT; nt++) {
        const int n = nt * 16 + ln;
        const float bv = bias[n];
        #pragma unroll
        for (int reg = 0; reg < 4; reg++) {
            const int t = wave * 16 + quad * 4 + reg;
            float val = acc[nt][reg] + bv;
            val = val > 0.f ? val : (__expf(val) - 1.f);   // ELU
            out[((size_t)v * 64 + t) * COUT + n] = (__bf16)val;
        }
    }
}

// ---------------------------------------------------------------------------
// head: spiral conv to 3 ch + actor offset -> [64][5023][3] f32
// ---------------------------------------------------------------------------
__global__ __launch_bounds__(256) void head_kernel(
    const __bf16* __restrict__ in, float* __restrict__ out,
    const int* __restrict__ idx, const __bf16* __restrict__ W,
    const float* __restrict__ bias, const float* __restrict__ actor)
{
    const int v = blockIdx.x;
    const int tid = threadIdx.x;
    const int wave = tid >> 6, lane = tid & 63, ln = lane & 15, quad = lane >> 4;
    __shared__ int sIdx[9];
    if (tid < 9) sIdx[tid] = idx[v * 9 + tid];
    __syncthreads();
    f32x4 acc = (f32x4){0.f, 0.f, 0.f, 0.f};
    const int tt = wave * 16 + ln;
    const int rown = ln < 3 ? ln : 0;
    #pragma unroll
    for (int kc = 0; kc < 9; kc++) {
        const int row = sIdx[kc];
        bf16x8 a = *(const bf16x8*)(in + ((size_t)row * 64 + tt) * 32 + quad * 8);
        bf16x8 b = *(const bf16x8*)(W + (size_t)rown * 288 + kc * 32 + quad * 8);
        acc = mfma16(a, b, acc);
    }
    if (ln < 3) {
        const float bv = bias[ln];
        const float av = actor[v * 3 + ln];
        #pragma unroll
        for (int reg = 0; reg < 4; reg++) {
            const int t = wave * 16 + quad * 4 + reg;
            out[((size_t)t * 5023 + v) * 3 + ln] = acc[reg] + bv + av;
        }
    }
}

extern "C" void kernel_launch(void* const* d_in, const int* in_sizes, int n_in,
                              void* d_out, int out_size, void* d_ws, size_t ws_size,
                              hipStream_t stream) {
    const float* audio = (const float*)d_in[0];
    const float* actor = (const float*)d_in[1];
    const float* Wih0  = (const float*)d_in[2];
    const float* Whh0  = (const float*)d_in[3];
    const float* b0    = (const float*)d_in[4];
    const float* WihL  = (const float*)d_in[5];
    const float* WhhL  = (const float*)d_in[6];
    const float* bLs   = (const float*)d_in[7];
    const float* fcW   = (const float*)d_in[8];
    const float* fcb   = (const float*)d_in[9];
    const float* c3W = (const float*)d_in[10]; const float* c3b = (const float*)d_in[11];
    const float* c2W = (const float*)d_in[12]; const float* c2b = (const float*)d_in[13];
    const float* c1W = (const float*)d_in[14]; const float* c1b = (const float*)d_in[15];
    const float* c0W = (const float*)d_in[16]; const float* c0b = (const float*)d_in[17];
    const float* hW  = (const float*)d_in[18]; const float* hb  = (const float*)d_in[19];
    const int* idx0 = (const int*)d_in[20];
    const int* idx1 = (const int*)d_in[21];
    const int* idx2 = (const int*)d_in[22];
    const int* idx3 = (const int*)d_in[23];
    const int* cols0 = (const int*)d_in[25]; const float* vals0 = (const float*)d_in[26];
    const int* cols1 = (const int*)d_in[28]; const float* vals1 = (const float*)d_in[29];
    const int* cols2 = (const int*)d_in[31]; const float* vals2 = (const float*)d_in[32];
    const int* cols3 = (const int*)d_in[34]; const float* vals3 = (const float*)d_in[35];

    char* ws = (char*)d_ws;
    unsigned int*   done = (unsigned int*)(ws + DONE_OFF);
    unsigned int*   exch = (unsigned int*)(ws + EXCH_OFF);
    __bf16*         GxB  = (__bf16*)(ws + GX_OFF);
    unsigned short* zbuf = (unsigned short*)(ws + ZBUF_OFF);
    char* arenaA = ws + ARENA_A;
    char* arenaB = ws + ARENA_B;

    __bf16* lw     = (__bf16*)arenaB;                 // lstm bf16 weights (dead after lstm)
    __bf16* convWb = (__bf16*)(ws + EXCH_OFF);        // overlays exch+Gx (dead after lstm)
    __bf16* fcWb   = (__bf16*)(arenaA + 393216);      // dead after fc

    __bf16* x4b = (__bf16*)arenaA;   // [20][64][128]
    __bf16* p3  = (__bf16*)arenaB;   // [79][64][128]
    __bf16* c3o = (__bf16*)arenaA;   // [79][64][128]
    __bf16* p2  = (__bf16*)arenaB;   // [314][64][128]
    __bf16* c2o = (__bf16*)arenaA;   // [314][64][64]
    __bf16* p1  = (__bf16*)arenaB;   // [1256][64][64]
    __bf16* c1o = (__bf16*)arenaA;   // [1256][64][64]
    __bf16* p0  = (__bf16*)arenaB;   // [5023][64][64]
    __bf16* c0o = (__bf16*)arenaA;   // [5023][64][32]

    // poison done+exch ourselves (payload-is-flag protocol must not depend on
    // harness poison semantics for the very first correctness call)
    hipMemsetAsync(ws, 0xAA, GX_OFF, stream);

    precvt_lstm<<<8192, 256, 0, stream>>>(Wih0, WihL, Whh0, WhhL, lw);
    lstm_kernel<<<16, 1024, 0, stream>>>(audio,
                                         lw + OW0, lw + OWL, lw + OH0, lw + OHL,
                                         b0, bLs, GxB, exch, done, zbuf);
    precvt_dec<<<1552, 256, 0, stream>>>(fcW, c3W, c2W, c1W, c0W, hW, fcWb, convWb);

    fc_kernel<<<40, 256, 0, stream>>>((const __bf16*)zbuf, fcWb, fcb, x4b);

    { int n = 79 * 64 * 128 / 8;
      pool_kernel<128><<<(n + 255) / 256, 256, 0, stream>>>(x4b, p3, cols3, vals3, 79);
      conv_kernel<128, 128><<<79, 256, 0, stream>>>(p3, c3o, idx3, convWb + 0, c3b); }
    { int n = 314 * 64 * 128 / 8;
      pool_kernel<128><<<(n + 255) / 256, 256, 0, stream>>>(c3o, p2, cols2, vals2, 314);
      conv_kernel<128, 64><<<314, 256, 0, stream>>>(p2, c2o, idx2, convWb + 147456, c2b); }
    { int n = 1256 * 64 * 64 / 8;
      pool_kernel<64><<<(n + 255) / 256, 256, 0, stream>>>(c2o, p1, cols1, vals1, 1256);
      conv_kernel<64, 64><<<1256, 256, 0, stream>>>(p1, c1o, idx1, convWb + 221184, c1b); }
    { int n = 5023 * 64 * 64 / 8;
      pool_kernel<64><<<(n + 255) / 256, 256, 0, stream>>>(c1o, p0, cols0, vals0, 5023);
      conv_kernel<64, 32><<<5023, 256, 0, stream>>>(p0, c0o, idx0, convWb + 258048, c0b); }

    head_kernel<<<5023, 256, 0, stream>>>(c0o, (float*)d_out, idx0, convWb + 276480, hb, actor);
}